// Round 3
// baseline (253.238 us; speedup 1.0000x reference)
//
#include <hip/hip_runtime.h>

typedef __attribute__((ext_vector_type(8))) short short8;
typedef __attribute__((ext_vector_type(4))) short short4_t;
typedef __attribute__((ext_vector_type(4))) float float4_t;
typedef __attribute__((ext_vector_type(4))) int int4_t;

#define CH_STRIDE 4096        // 64*64 spatial per channel
#define IMG_STRIDE 524288     // 128 channels * 4096
#define HW 4096
#define V520 520              // Vt row stride (shorts); 1040B rows keep 16B align

// float -> bf16 bits, round-to-nearest-even (finite inputs only)
static __device__ __forceinline__ short f2b(float x) {
    unsigned u = __builtin_bit_cast(unsigned, x);
    u = (u + 0x7fffu + ((u >> 16) & 1u)) >> 16;
    return (short)u;
}
static __device__ __forceinline__ float bitsf(unsigned u) { return __builtin_bit_cast(float, u); }
static __device__ __forceinline__ unsigned bitsu(float f) { return __builtin_bit_cast(unsigned, f); }

// Fused CSWin block: flash attention (S^T = K*Q^T, bpermute P-exchange, O^T = V^T*P^T)
// + depthwise 3x3 conv rpe from the LDS-resident V, all in one launch.
// Grid 512 = (nw, b, head) with nw in the high bits so nw-adjacent blocks (which
// share split 64B cache lines) land on the same XCD under %8 round-robin.
__global__ __launch_bounds__(512, 4) void cswin_fused(
    const float* __restrict__ temp, const float* __restrict__ cw,
    const float* __restrict__ cb, float* __restrict__ out)
{
    __shared__ short Kc[64 * 40];      // [key][d] pad-40 (current chunk)
    __shared__ short Vt[32 * V520];    // [d][l]   full 512-key window, persistent

    int bx = blockIdx.x;
    int nw = bx >> 6;          // window column 0..7
    int r  = bx & 63;
    int b  = r >> 2;           // batch 0..15
    int n  = r & 3;            // head 0..3

    int t    = threadIdx.x;
    int wv   = t >> 6;         // wave 0..7
    int lane = t & 63;
    int mr   = lane & 15;
    int q    = lane >> 4;

    const float* tq = temp + (size_t)b * 3 * IMG_STRIDE + (size_t)(n * 32) * CH_STRIDE + nw * 8;
    const float* tk = tq + IMG_STRIDE;
    const float* tv = tk + IMG_STRIDE;

    int row0 = wv * 64;        // this wave's 64 q-rows
    const float qscale = 0.2550348889072310f;   // (1/sqrt(32)) * log2(e)

    // Q fragments (B-operand): lane holds Q[row0+qt*16+mr][q*8+j] * qscale
    short8 Qf[4];
    #pragma unroll
    for (int qt = 0; qt < 4; ++qt) {
        int l = row0 + qt * 16 + mr;
        int sp = (l >> 3) * 64 + (l & 7);
        short8 f;
        #pragma unroll
        for (int j = 0; j < 8; ++j)
            f[j] = f2b(tq[(q * 8 + j) * CH_STRIDE + sp] * qscale);
        Qf[qt] = f;
    }

    float4_t zero4 = {0.f, 0.f, 0.f, 0.f};
    float4_t acc[2][4];
    #pragma unroll
    for (int dt = 0; dt < 2; ++dt)
        #pragma unroll
        for (int qt = 0; qt < 4; ++qt)
            acc[dt][qt] = zero4;
    float lsum[4] = {0.f, 0.f, 0.f, 0.f};

    // loader mapping: 512 threads = 32 d x 16 key-quads
    int ld  = t >> 4;          // channel d 0..31
    int seg = t & 15;          // 4 consecutive keys
    const float* tkld = tk + (size_t)ld * CH_STRIDE;
    const float* tvld = tv + (size_t)ld * CH_STRIDE;

    // prefetch chunk 0 into registers
    int lb0 = seg * 4;
    int sp0 = (lb0 >> 3) * 64 + (lb0 & 7);
    float4_t k4 = *reinterpret_cast<const float4_t*>(tkld + sp0);
    float4_t v4 = *reinterpret_cast<const float4_t*>(tvld + sp0);

    int s0lane = (q & 1) * 32 + mr;    // bpermute sources for the P exchange
    int s1lane = s0lane + 16;
    bool hiq = (q >= 2);

    for (int ch = 0; ch < 8; ++ch) {
        __syncthreads();   // all waves done with previous chunk's Kc
        {
            int kl = seg * 4;
            Kc[(kl + 0) * 40 + ld] = f2b(k4.x);
            Kc[(kl + 1) * 40 + ld] = f2b(k4.y);
            Kc[(kl + 2) * 40 + ld] = f2b(k4.z);
            Kc[(kl + 3) * 40 + ld] = f2b(k4.w);
            short4_t vs = { f2b(v4.x), f2b(v4.y), f2b(v4.z), f2b(v4.w) };
            *reinterpret_cast<short4_t*>(&Vt[ld * V520 + ch * 64 + kl]) = vs;
        }
        if (ch < 7) {      // next chunk's loads stay in flight across the barrier
            int lb = (ch + 1) * 64 + seg * 4;
            int sp = (lb >> 3) * 64 + (lb & 7);
            k4 = *reinterpret_cast<const float4_t*>(tkld + sp);
            v4 = *reinterpret_cast<const float4_t*>(tvld + sp);
        }
        __syncthreads();

        #pragma unroll
        for (int g = 0; g < 2; ++g) {
            // S^T tiles: D[m=key][n=qrow], keys g*32..g*32+31 (local to chunk)
            short8 KaA = *reinterpret_cast<const short8*>(&Kc[((2 * g) * 16 + mr) * 40 + q * 8]);
            short8 KaB = *reinterpret_cast<const short8*>(&Kc[((2 * g + 1) * 16 + mr) * 40 + q * 8]);
            unsigned pa0[4], pa1[4], pb0[4], pb1[4];
            #pragma unroll
            for (int qt = 0; qt < 4; ++qt) {
                float4_t sA = __builtin_amdgcn_mfma_f32_16x16x32_bf16(KaA, Qf[qt], zero4, 0, 0, 0);
                float4_t sB = __builtin_amdgcn_mfma_f32_16x16x32_bf16(KaB, Qf[qt], zero4, 0, 0, 0);
                float eA0 = __builtin_amdgcn_exp2f(sA.x), eA1 = __builtin_amdgcn_exp2f(sA.y);
                float eA2 = __builtin_amdgcn_exp2f(sA.z), eA3 = __builtin_amdgcn_exp2f(sA.w);
                float eB0 = __builtin_amdgcn_exp2f(sB.x), eB1 = __builtin_amdgcn_exp2f(sB.y);
                float eB2 = __builtin_amdgcn_exp2f(sB.z), eB3 = __builtin_amdgcn_exp2f(sB.w);
                lsum[qt] += ((eA0 + eA1) + (eA2 + eA3)) + ((eB0 + eB1) + (eB2 + eB3));
                // pack pairs (truncation) with one v_perm each: [lo16=e_even, hi16=e_odd]
                pa0[qt] = __builtin_amdgcn_perm(bitsu(eA1), bitsu(eA0), 0x07060302u);
                pa1[qt] = __builtin_amdgcn_perm(bitsu(eA3), bitsu(eA2), 0x07060302u);
                pb0[qt] = __builtin_amdgcn_perm(bitsu(eB1), bitsu(eB0), 0x07060302u);
                pb1[qt] = __builtin_amdgcn_perm(bitsu(eB3), bitsu(eB2), 0x07060302u);
            }
            // V^T A-fragments for this 32-key group
            int base = ch * 64 + g * 32 + q * 8;
            short8 Va0 = *reinterpret_cast<const short8*>(&Vt[mr * V520 + base]);
            short8 Va1 = *reinterpret_cast<const short8*>(&Vt[(16 + mr) * V520 + base]);
            #pragma unroll
            for (int qt = 0; qt < 4; ++qt) {
                // exchange C-layout P (keys q*4+r per quad) -> B-operand (keys q*8+j)
                int x0 = __shfl((int)pa0[qt], s0lane); int y0 = __shfl((int)pb0[qt], s0lane);
                int x1 = __shfl((int)pa1[qt], s0lane); int y1 = __shfl((int)pb1[qt], s0lane);
                int x2 = __shfl((int)pa0[qt], s1lane); int y2 = __shfl((int)pb0[qt], s1lane);
                int x3 = __shfl((int)pa1[qt], s1lane); int y3 = __shfl((int)pb1[qt], s1lane);
                int4_t pi = { hiq ? y0 : x0, hiq ? y1 : x1, hiq ? y2 : x2, hiq ? y3 : x3 };
                short8 Pb = __builtin_bit_cast(short8, pi);
                acc[0][qt] = __builtin_amdgcn_mfma_f32_16x16x32_bf16(Va0, Pb, acc[0][qt], 0, 0, 0);
                acc[1][qt] = __builtin_amdgcn_mfma_f32_16x16x32_bf16(Va1, Pb, acc[1][qt], 0, 0, 0);
            }
        }
    }

    // softmax denominators: reduce across quads, invert
    float inv[4];
    #pragma unroll
    for (int qt = 0; qt < 4; ++qt) {
        float v = lsum[qt];
        v += __shfl_xor(v, 16);
        v += __shfl_xor(v, 32);
        inv[qt] = 1.0f / v;
    }

    // O store: lane holds O[qrow=row0+qt*16+mr][c = n*32 + dt*16 + q*4 + r]
    float* outb = out + (size_t)b * HW * 128 + nw * 8 * 128 + n * 32;
    #pragma unroll
    for (int qt = 0; qt < 4; ++qt) {
        int l = row0 + qt * 16 + mr;
        size_t basep = (size_t)((l >> 3) * 64 + (l & 7)) * 128;
        #pragma unroll
        for (int dt = 0; dt < 2; ++dt) {
            float4_t o = acc[dt][qt] * inv[qt];
            *reinterpret_cast<float4_t*>(outb + basep + dt * 16 + q * 4) = o;
        }
    }

    __syncthreads();   // O-stores visible block-wide; Vt stable since last chunk

    // ---- depthwise 3x3 conv + bias (window-local SAME pad) from LDS V, RMW out
    int c4 = (t & 7) * 4;      // relative channel 0..28
    int h  = t >> 3;           // 0..63
    float4_t outv[8];
    #pragma unroll
    for (int cc = 0; cc < 4; ++cc) {
        int c = c4 + cc;
        float w9[9];
        #pragma unroll
        for (int i = 0; i < 9; ++i) w9[i] = cw[(n * 32 + c) * 9 + i];
        float bias = cb[n * 32 + c];
        float rv[3][8];
        #pragma unroll
        for (int rr = 0; rr < 3; ++rr) {
            int hh = h - 1 + rr;
            if (hh >= 0 && hh < 64) {
                short8 u = *reinterpret_cast<const short8*>(&Vt[c * V520 + hh * 8]);
                #pragma unroll
                for (int j = 0; j < 8; ++j)
                    rv[rr][j] = bitsf(((unsigned)(unsigned short)u[j]) << 16);
            } else {
                #pragma unroll
                for (int j = 0; j < 8; ++j) rv[rr][j] = 0.f;
            }
        }
        #pragma unroll
        for (int w = 0; w < 8; ++w) {
            float o = bias;
            #pragma unroll
            for (int rr = 0; rr < 3; ++rr) {
                if (w > 0) o += rv[rr][w - 1] * w9[rr * 3 + 0];
                o += rv[rr][w] * w9[rr * 3 + 1];
                if (w < 7) o += rv[rr][w + 1] * w9[rr * 3 + 2];
            }
            outv[w][cc] = o;
        }
    }
    #pragma unroll
    for (int w = 0; w < 8; ++w) {
        size_t off = (size_t)h * 8192 + w * 128 + c4;
        float4_t cur = *reinterpret_cast<const float4_t*>(outb + off);
        cur += outv[w];
        *reinterpret_cast<float4_t*>(outb + off) = cur;
    }
}

extern "C" void kernel_launch(void* const* d_in, const int* in_sizes, int n_in,
                              void* d_out, int out_size, void* d_ws, size_t ws_size,
                              hipStream_t stream) {
    const float* temp = (const float*)d_in[0];
    const float* cw   = (const float*)d_in[1];
    const float* cb   = (const float*)d_in[2];
    float* out = (float*)d_out;
    hipLaunchKernelGGL(cswin_fused, dim3(512), dim3(512), 0, stream, temp, cw, cb, out);
}

// Round 4
// 191.616 us; speedup vs baseline: 1.3216x; 1.3216x over previous
//
#include <hip/hip_runtime.h>

typedef __attribute__((ext_vector_type(8))) short short8;
typedef __attribute__((ext_vector_type(4))) short short4_t;
typedef __attribute__((ext_vector_type(4))) float float4_t;
typedef __attribute__((ext_vector_type(4))) int int4_t;

#define CH_STRIDE 4096        // 64*64 spatial per channel
#define IMG_STRIDE 524288     // 128 channels * 4096
#define HW 4096
#define V520 520              // Vt row stride (shorts); 1040B rows keep 16B align

// float -> bf16 bits, round-to-nearest-even (finite inputs only)
static __device__ __forceinline__ short f2b(float x) {
    unsigned u = __builtin_bit_cast(unsigned, x);
    u = (u + 0x7fffu + ((u >> 16) & 1u)) >> 16;
    return (short)u;
}
static __device__ __forceinline__ float bitsf(unsigned u) { return __builtin_bit_cast(float, u); }
static __device__ __forceinline__ unsigned bitsu(float f) { return __builtin_bit_cast(unsigned, f); }

// Fused CSWin block: flash attention (S^T = K*Q^T, bpermute P-exchange, O^T = V^T*P^T)
// + depthwise 3x3 conv rpe from the LDS-resident V, all in one launch.
// Grid 512 = (nw, b, head) with nw in the high bits so nw-adjacent blocks (which
// share split 64B cache lines) land on the same XCD under %8 round-robin.
// NOTE: __launch_bounds__(512) with NO min-waves arg — (512,4) capped the
// unified VGPR+AGPR file at 128 and caused ~190 MB of scratch spill traffic
// (R3: VGPR_Count 64, WRITE_SIZE 218 MB, 2.2x regression).
__global__ __launch_bounds__(512) void cswin_fused(
    const float* __restrict__ temp, const float* __restrict__ cw,
    const float* __restrict__ cb, float* __restrict__ out)
{
    __shared__ short Kc[64 * 40];      // [key][d] pad-40 (current chunk)
    __shared__ short Vt[32 * V520];    // [d][l]   full 512-key window, persistent

    int bx = blockIdx.x;
    int nw = bx >> 6;          // window column 0..7
    int r  = bx & 63;
    int b  = r >> 2;           // batch 0..15
    int n  = r & 3;            // head 0..3

    int t    = threadIdx.x;
    int wv   = t >> 6;         // wave 0..7
    int lane = t & 63;
    int mr   = lane & 15;
    int q    = lane >> 4;

    const float* tq = temp + (size_t)b * 3 * IMG_STRIDE + (size_t)(n * 32) * CH_STRIDE + nw * 8;
    const float* tk = tq + IMG_STRIDE;
    const float* tv = tk + IMG_STRIDE;

    int row0 = wv * 64;        // this wave's 64 q-rows
    const float qscale = 0.2550348889072310f;   // (1/sqrt(32)) * log2(e)

    // Q fragments (B-operand): lane holds Q[row0+qt*16+mr][q*8+j] * qscale
    short8 Qf[4];
    #pragma unroll
    for (int qt = 0; qt < 4; ++qt) {
        int l = row0 + qt * 16 + mr;
        int sp = (l >> 3) * 64 + (l & 7);
        short8 f;
        #pragma unroll
        for (int j = 0; j < 8; ++j)
            f[j] = f2b(tq[(q * 8 + j) * CH_STRIDE + sp] * qscale);
        Qf[qt] = f;
    }

    float4_t zero4 = {0.f, 0.f, 0.f, 0.f};
    float4_t acc[2][4];
    #pragma unroll
    for (int dt = 0; dt < 2; ++dt)
        #pragma unroll
        for (int qt = 0; qt < 4; ++qt)
            acc[dt][qt] = zero4;
    float lsum[4] = {0.f, 0.f, 0.f, 0.f};

    // loader mapping: 512 threads = 32 d x 16 key-quads
    int ld  = t >> 4;          // channel d 0..31
    int seg = t & 15;          // 4 consecutive keys
    const float* tkld = tk + (size_t)ld * CH_STRIDE;
    const float* tvld = tv + (size_t)ld * CH_STRIDE;

    // prefetch chunk 0 into registers
    int lb0 = seg * 4;
    int sp0 = (lb0 >> 3) * 64 + (lb0 & 7);
    float4_t k4 = *reinterpret_cast<const float4_t*>(tkld + sp0);
    float4_t v4 = *reinterpret_cast<const float4_t*>(tvld + sp0);

    int s0lane = (q & 1) * 32 + mr;    // bpermute sources for the P exchange
    int s1lane = s0lane + 16;
    bool hiq = (q >= 2);

    for (int ch = 0; ch < 8; ++ch) {
        __syncthreads();   // all waves done with previous chunk's Kc
        {
            int kl = seg * 4;
            Kc[(kl + 0) * 40 + ld] = f2b(k4.x);
            Kc[(kl + 1) * 40 + ld] = f2b(k4.y);
            Kc[(kl + 2) * 40 + ld] = f2b(k4.z);
            Kc[(kl + 3) * 40 + ld] = f2b(k4.w);
            short4_t vs = { f2b(v4.x), f2b(v4.y), f2b(v4.z), f2b(v4.w) };
            *reinterpret_cast<short4_t*>(&Vt[ld * V520 + ch * 64 + kl]) = vs;
        }
        if (ch < 7) {      // next chunk's loads stay in flight across the barrier
            int lb = (ch + 1) * 64 + seg * 4;
            int sp = (lb >> 3) * 64 + (lb & 7);
            k4 = *reinterpret_cast<const float4_t*>(tkld + sp);
            v4 = *reinterpret_cast<const float4_t*>(tvld + sp);
        }
        __syncthreads();

        #pragma unroll
        for (int g = 0; g < 2; ++g) {
            // S^T tiles: D[m=key][n=qrow], keys g*32..g*32+31 (local to chunk)
            short8 KaA = *reinterpret_cast<const short8*>(&Kc[((2 * g) * 16 + mr) * 40 + q * 8]);
            short8 KaB = *reinterpret_cast<const short8*>(&Kc[((2 * g + 1) * 16 + mr) * 40 + q * 8]);
            unsigned pa0[4], pa1[4], pb0[4], pb1[4];
            #pragma unroll
            for (int qt = 0; qt < 4; ++qt) {
                float4_t sA = __builtin_amdgcn_mfma_f32_16x16x32_bf16(KaA, Qf[qt], zero4, 0, 0, 0);
                float4_t sB = __builtin_amdgcn_mfma_f32_16x16x32_bf16(KaB, Qf[qt], zero4, 0, 0, 0);
                float eA0 = __builtin_amdgcn_exp2f(sA.x), eA1 = __builtin_amdgcn_exp2f(sA.y);
                float eA2 = __builtin_amdgcn_exp2f(sA.z), eA3 = __builtin_amdgcn_exp2f(sA.w);
                float eB0 = __builtin_amdgcn_exp2f(sB.x), eB1 = __builtin_amdgcn_exp2f(sB.y);
                float eB2 = __builtin_amdgcn_exp2f(sB.z), eB3 = __builtin_amdgcn_exp2f(sB.w);
                lsum[qt] += ((eA0 + eA1) + (eA2 + eA3)) + ((eB0 + eB1) + (eB2 + eB3));
                // pack pairs (truncation) with one v_perm each: [lo16=e_even, hi16=e_odd]
                pa0[qt] = __builtin_amdgcn_perm(bitsu(eA1), bitsu(eA0), 0x07060302u);
                pa1[qt] = __builtin_amdgcn_perm(bitsu(eA3), bitsu(eA2), 0x07060302u);
                pb0[qt] = __builtin_amdgcn_perm(bitsu(eB1), bitsu(eB0), 0x07060302u);
                pb1[qt] = __builtin_amdgcn_perm(bitsu(eB3), bitsu(eB2), 0x07060302u);
            }
            // V^T A-fragments for this 32-key group
            int base = ch * 64 + g * 32 + q * 8;
            short8 Va0 = *reinterpret_cast<const short8*>(&Vt[mr * V520 + base]);
            short8 Va1 = *reinterpret_cast<const short8*>(&Vt[(16 + mr) * V520 + base]);
            #pragma unroll
            for (int qt = 0; qt < 4; ++qt) {
                // exchange C-layout P (keys q*4+r per quad) -> B-operand (keys q*8+j)
                int x0 = __shfl((int)pa0[qt], s0lane); int y0 = __shfl((int)pb0[qt], s0lane);
                int x1 = __shfl((int)pa1[qt], s0lane); int y1 = __shfl((int)pb1[qt], s0lane);
                int x2 = __shfl((int)pa0[qt], s1lane); int y2 = __shfl((int)pb0[qt], s1lane);
                int x3 = __shfl((int)pa1[qt], s1lane); int y3 = __shfl((int)pb1[qt], s1lane);
                int4_t pi = { hiq ? y0 : x0, hiq ? y1 : x1, hiq ? y2 : x2, hiq ? y3 : x3 };
                short8 Pb = __builtin_bit_cast(short8, pi);
                acc[0][qt] = __builtin_amdgcn_mfma_f32_16x16x32_bf16(Va0, Pb, acc[0][qt], 0, 0, 0);
                acc[1][qt] = __builtin_amdgcn_mfma_f32_16x16x32_bf16(Va1, Pb, acc[1][qt], 0, 0, 0);
            }
        }
    }

    // softmax denominators: reduce across quads, invert
    float inv[4];
    #pragma unroll
    for (int qt = 0; qt < 4; ++qt) {
        float v = lsum[qt];
        v += __shfl_xor(v, 16);
        v += __shfl_xor(v, 32);
        inv[qt] = 1.0f / v;
    }

    // O store: lane holds O[qrow=row0+qt*16+mr][c = n*32 + dt*16 + q*4 + r]
    float* outb = out + (size_t)b * HW * 128 + nw * 8 * 128 + n * 32;
    #pragma unroll
    for (int qt = 0; qt < 4; ++qt) {
        int l = row0 + qt * 16 + mr;
        size_t basep = (size_t)((l >> 3) * 64 + (l & 7)) * 128;
        #pragma unroll
        for (int dt = 0; dt < 2; ++dt) {
            float4_t o = acc[dt][qt] * inv[qt];
            *reinterpret_cast<float4_t*>(outb + basep + dt * 16 + q * 4) = o;
        }
    }

    __syncthreads();   // O-stores visible block-wide; Vt stable since last chunk

    // ---- depthwise 3x3 conv + bias (window-local SAME pad) from LDS V, RMW out
    int c4 = (t & 7) * 4;      // relative channel 0..28
    int h  = t >> 3;           // 0..63
    float4_t outv[8];
    #pragma unroll
    for (int cc = 0; cc < 4; ++cc) {
        int c = c4 + cc;
        float w9[9];
        #pragma unroll
        for (int i = 0; i < 9; ++i) w9[i] = cw[(n * 32 + c) * 9 + i];
        float bias = cb[n * 32 + c];
        float rv[3][8];
        #pragma unroll
        for (int rr = 0; rr < 3; ++rr) {
            int hh = h - 1 + rr;
            if (hh >= 0 && hh < 64) {
                short8 u = *reinterpret_cast<const short8*>(&Vt[c * V520 + hh * 8]);
                #pragma unroll
                for (int j = 0; j < 8; ++j)
                    rv[rr][j] = bitsf(((unsigned)(unsigned short)u[j]) << 16);
            } else {
                #pragma unroll
                for (int j = 0; j < 8; ++j) rv[rr][j] = 0.f;
            }
        }
        #pragma unroll
        for (int w = 0; w < 8; ++w) {
            float o = bias;
            #pragma unroll
            for (int rr = 0; rr < 3; ++rr) {
                if (w > 0) o += rv[rr][w - 1] * w9[rr * 3 + 0];
                o += rv[rr][w] * w9[rr * 3 + 1];
                if (w < 7) o += rv[rr][w + 1] * w9[rr * 3 + 2];
            }
            outv[w][cc] = o;
        }
    }
    #pragma unroll
    for (int w = 0; w < 8; ++w) {
        size_t off = (size_t)h * 8192 + w * 128 + c4;
        float4_t cur = *reinterpret_cast<const float4_t*>(outb + off);
        cur += outv[w];
        *reinterpret_cast<float4_t*>(outb + off) = cur;
    }
}

extern "C" void kernel_launch(void* const* d_in, const int* in_sizes, int n_in,
                              void* d_out, int out_size, void* d_ws, size_t ws_size,
                              hipStream_t stream) {
    const float* temp = (const float*)d_in[0];
    const float* cw   = (const float*)d_in[1];
    const float* cb   = (const float*)d_in[2];
    float* out = (float*)d_out;
    hipLaunchKernelGGL(cswin_fused, dim3(512), dim3(512), 0, stream, temp, cw, cb, out);
}